// Round 1
// baseline (333.248 us; speedup 1.0000x reference)
//
#include <hip/hip_runtime.h>
#include <hip/hip_bf16.h>
#include <stdint.h>

#define H_DIM 1024
#define S_DIM 4096
#define B_DIM 4

typedef __bf16 bf16x8 __attribute__((ext_vector_type(8)));
typedef float f32x4 __attribute__((ext_vector_type(4)));

__device__ __forceinline__ unsigned short f2bf(float f) {
    union { float f; uint32_t u; } v; v.f = f;
    uint32_t u = v.u;
    uint32_t r = (u + 0x7FFFu + ((u >> 16) & 1u)) >> 16;  // round-to-nearest-even
    return (unsigned short)r;
}

// X[b][s][h] fp32 -> Xb[b][s][h] bf16  and  XT[b][h][s] bf16
__global__ void cast_x_kernel(const float* __restrict__ X,
                              unsigned short* __restrict__ Xb,
                              unsigned short* __restrict__ XT) {
    __shared__ float tile[32][33];
    const int b  = blockIdx.z;
    const int h0 = blockIdx.x * 32;
    const int s0 = blockIdx.y * 32;
    const int tx = threadIdx.x;   // 0..31
    const int ty = threadIdx.y;   // 0..7
    const float* src = X + ((size_t)b * S_DIM + s0) * H_DIM + h0;
#pragma unroll
    for (int i = 0; i < 4; ++i) {
        int s = ty + 8 * i;
        float v = src[(size_t)s * H_DIM + tx];
        tile[s][tx] = v;
        Xb[((size_t)b * S_DIM + s0 + s) * H_DIM + h0 + tx] = f2bf(v);
    }
    __syncthreads();
#pragma unroll
    for (int i = 0; i < 4; ++i) {
        int hh = ty + 8 * i;
        XT[((size_t)b * H_DIM + h0 + hh) * S_DIM + s0 + tx] = f2bf(tile[tx][hh]);
    }
}

// W[o][h'] fp32 -> WT[h'][o] bf16
__global__ void cast_w_kernel(const float* __restrict__ W,
                              unsigned short* __restrict__ WT) {
    __shared__ float tile[32][33];
    const int b0 = blockIdx.x * 32;   // cols of W (h')
    const int o0 = blockIdx.y * 32;   // rows of W (o)
    const int tx = threadIdx.x;
    const int ty = threadIdx.y;
#pragma unroll
    for (int i = 0; i < 4; ++i) {
        int o = ty + 8 * i;
        tile[o][tx] = W[(size_t)(o0 + o) * H_DIM + b0 + tx];
    }
    __syncthreads();
#pragma unroll
    for (int i = 0; i < 4; ++i) {
        int bb = ty + 8 * i;
        WT[(size_t)(b0 + bb) * H_DIM + o0 + tx] = f2bf(tile[tx][bb]);
    }
}

// C[M,N] = A[M,K] @ Bt[N,K]^T  (bf16 in, fp32 accum, OutT out)
// 128x128 tile, BK=64, 256 threads (4 waves), each wave 64x64 via 4x4 frags
// of v_mfma_f32_16x16x32_bf16. LDS layout fragment-major [BK/8][128][8]:
// element (m,k) at ((k/8)*128 + m)*8 + k%8 -> global_load_lds-compatible
// (chunk c covers LDS [c*512,+512) = lane*16B contiguous) AND conflict-free
// ds_read_b128 (consecutive m -> consecutive 16B blocks).
template <typename OutT>
__global__ __launch_bounds__(256, 2)
void gemm_bt_kernel(const unsigned short* __restrict__ A,
                    const unsigned short* __restrict__ Bt,
                    OutT* __restrict__ C,
                    int K, int lda, int ldb, int ldc,
                    size_t sA, size_t sB, size_t sC) {
    __shared__ __align__(16) unsigned short As[8192];
    __shared__ __align__(16) unsigned short Bs[8192];

    const int tid  = threadIdx.x;
    const int w    = tid >> 6;
    const int lane = tid & 63;
    const int wm   = w & 1;
    const int wn   = w >> 1;
    const int q    = lane >> 4;    // 0..3
    const int col  = lane & 15;

    const int tileN = blockIdx.x * 128;
    const int tileM = blockIdx.y * 128;
    const int bz    = blockIdx.z;

    const unsigned short* Ab = A + sA * bz;
    const unsigned short* Bb = Bt + sB * bz;

    const unsigned short* gA[4];
    const unsigned short* gB[4];
    int ldsOff[4];
#pragma unroll
    for (int i = 0; i < 4; ++i) {
        int chunk = (w << 2) | i;              // 0..15, uniform per wave
        int m  = ((chunk & 1) << 6) | lane;    // 0..127
        int k8 = chunk >> 1;                   // 0..7
        gA[i] = Ab + (size_t)(tileM + m) * lda + k8 * 8;
        gB[i] = Bb + (size_t)(tileN + m) * ldb + k8 * 8;
        ldsOff[i] = chunk * 512;
    }

    f32x4 acc[4][4];
#pragma unroll
    for (int r = 0; r < 4; ++r)
#pragma unroll
        for (int c = 0; c < 4; ++c)
            acc[r][c] = (f32x4){0.f, 0.f, 0.f, 0.f};

    for (int k0 = 0; k0 < K; k0 += 64) {
        __syncthreads();
#pragma unroll
        for (int i = 0; i < 4; ++i) {
            __builtin_amdgcn_global_load_lds(
                (const __attribute__((address_space(1))) void*)gA[i],
                (__attribute__((address_space(3))) void*)&As[ldsOff[i]],
                16, 0, 0);
            __builtin_amdgcn_global_load_lds(
                (const __attribute__((address_space(1))) void*)gB[i],
                (__attribute__((address_space(3))) void*)&Bs[ldsOff[i]],
                16, 0, 0);
            gA[i] += 64;
            gB[i] += 64;
        }
        __syncthreads();
#pragma unroll
        for (int kc = 0; kc < 2; ++kc) {       // kk = kc*32
            bf16x8 av[4], bv[4];
#pragma unroll
            for (int r = 0; r < 4; ++r)
                av[r] = *(const bf16x8*)&As[(((kc * 4 + q) * 128) + wm * 64 + r * 16 + col) * 8];
#pragma unroll
            for (int c = 0; c < 4; ++c)
                bv[c] = *(const bf16x8*)&Bs[(((kc * 4 + q) * 128) + wn * 64 + c * 16 + col) * 8];
#pragma unroll
            for (int r = 0; r < 4; ++r)
#pragma unroll
                for (int c = 0; c < 4; ++c)
                    acc[r][c] = __builtin_amdgcn_mfma_f32_16x16x32_bf16(
                        av[r], bv[c], acc[r][c], 0, 0, 0);
        }
    }

    OutT* Cb = C + sC * bz;
#pragma unroll
    for (int r = 0; r < 4; ++r) {
#pragma unroll
        for (int c = 0; c < 4; ++c) {
            int row0 = tileM + wm * 64 + r * 16 + q * 4;
            int colg = tileN + wn * 64 + c * 16 + col;
#pragma unroll
            for (int v = 0; v < 4; ++v) {
                float val = acc[r][c][v];
                if constexpr (sizeof(OutT) == 2) {
                    Cb[(size_t)(row0 + v) * ldc + colg] = (OutT)f2bf(val);
                } else {
                    Cb[(size_t)(row0 + v) * ldc + colg] = (OutT)val;
                }
            }
        }
    }
}

extern "C" void kernel_launch(void* const* d_in, const int* in_sizes, int n_in,
                              void* d_out, int out_size, void* d_ws, size_t ws_size,
                              hipStream_t stream) {
    const float* X = (const float*)d_in[0];   // [4,4096,1024]
    const float* W = (const float*)d_in[1];   // [1024,1024]
    float* out = (float*)d_out;               // [4,4096,1024] fp32

    char* ws = (char*)d_ws;
    // ws layout (bytes):
    unsigned short* Xb = (unsigned short*)(ws);              // 33,554,432  [b][s][h]
    unsigned short* XT = (unsigned short*)(ws + 33554432);   // 33,554,432  [b][h][s]
    unsigned short* WT = (unsigned short*)(ws + 67108864);   //  2,097,152  [h'][o]
    unsigned short* G  = (unsigned short*)(ws + 69206016);   //  8,388,608  [b][o][h]
    unsigned short* MT = (unsigned short*)(ws + 77594624);   //  8,388,608  [b][h''][h]
    // total 85,983,232 bytes

    // 1) casts + transposes
    cast_x_kernel<<<dim3(H_DIM / 32, S_DIM / 32, B_DIM), dim3(32, 8), 0, stream>>>(X, Xb, XT);
    cast_w_kernel<<<dim3(H_DIM / 32, H_DIM / 32, 1), dim3(32, 8), 0, stream>>>(W, WT);

    // 2) G_b = XT_b @ XT_b^T   [1024 x 1024], K = 4096
    gemm_bt_kernel<unsigned short><<<dim3(8, 8, B_DIM), 256, 0, stream>>>(
        XT, XT, G, S_DIM, S_DIM, S_DIM, H_DIM,
        (size_t)H_DIM * S_DIM, (size_t)H_DIM * S_DIM, (size_t)H_DIM * H_DIM);

    // 3) MT_b = G_b @ WT^T  (= G W, valid since G symmetric)  [1024 x 1024], K = 1024
    gemm_bt_kernel<unsigned short><<<dim3(8, 8, B_DIM), 256, 0, stream>>>(
        G, WT, MT, H_DIM, H_DIM, H_DIM, H_DIM,
        (size_t)H_DIM * H_DIM, (size_t)0, (size_t)H_DIM * H_DIM);

    // 4) att_b = Xb_b @ MT_b^T   [4096 x 1024], K = 1024, fp32 out
    gemm_bt_kernel<float><<<dim3(8, S_DIM / 128, B_DIM), 256, 0, stream>>>(
        Xb, MT, out, H_DIM, H_DIM, H_DIM, H_DIM,
        (size_t)S_DIM * H_DIM, (size_t)H_DIM * H_DIM, (size_t)S_DIM * H_DIM);
}

// Round 3
// 319.889 us; speedup vs baseline: 1.0418x; 1.0418x over previous
//
#include <hip/hip_runtime.h>
#include <hip/hip_bf16.h>
#include <stdint.h>

#define H_DIM 1024
#define S_DIM 4096
#define B_DIM 4

typedef __bf16 bf16x8 __attribute__((ext_vector_type(8)));
typedef float f32x4 __attribute__((ext_vector_type(4)));
typedef unsigned short u16x4 __attribute__((ext_vector_type(4)));

__device__ __forceinline__ unsigned short f2bf(float f) {
    union { float f; uint32_t u; } v; v.f = f;
    uint32_t u = v.u;
    uint32_t r = (u + 0x7FFFu + ((u >> 16) & 1u)) >> 16;  // round-to-nearest-even
    return (unsigned short)r;
}

// X[b][s][h] fp32 -> Xb[b][s][h] bf16  and  XT[b][h][s] bf16
__global__ void cast_x_kernel(const float* __restrict__ X,
                              unsigned short* __restrict__ Xb,
                              unsigned short* __restrict__ XT) {
    __shared__ float tile[32][33];
    const int b  = blockIdx.z;
    const int h0 = blockIdx.x * 32;
    const int s0 = blockIdx.y * 32;
    const int tx = threadIdx.x;   // 0..31
    const int ty = threadIdx.y;   // 0..7
    const float* src = X + ((size_t)b * S_DIM + s0) * H_DIM + h0;
#pragma unroll
    for (int i = 0; i < 4; ++i) {
        int s = ty + 8 * i;
        float v = src[(size_t)s * H_DIM + tx];
        tile[s][tx] = v;
        Xb[((size_t)b * S_DIM + s0 + s) * H_DIM + h0 + tx] = f2bf(v);
    }
    __syncthreads();
#pragma unroll
    for (int i = 0; i < 4; ++i) {
        int hh = ty + 8 * i;
        XT[((size_t)b * H_DIM + h0 + hh) * S_DIM + s0 + tx] = f2bf(tile[tx][hh]);
    }
}

// W[o][h'] fp32 -> WT[h'][o] bf16
__global__ void cast_w_kernel(const float* __restrict__ W,
                              unsigned short* __restrict__ WT) {
    __shared__ float tile[32][33];
    const int b0 = blockIdx.x * 32;   // cols of W (h')
    const int o0 = blockIdx.y * 32;   // rows of W (o)
    const int tx = threadIdx.x;
    const int ty = threadIdx.y;
#pragma unroll
    for (int i = 0; i < 4; ++i) {
        int o = ty + 8 * i;
        tile[o][tx] = W[(size_t)(o0 + o) * H_DIM + b0 + tx];
    }
    __syncthreads();
#pragma unroll
    for (int i = 0; i < 4; ++i) {
        int bb = ty + 8 * i;
        WT[(size_t)(b0 + bb) * H_DIM + o0 + tx] = f2bf(tile[tx][bb]);
    }
}

// Sum NSPLIT fp32 partials (each sSplit apart) and cast to bf16.
template <int NSPLIT>
__global__ void reduce_cast_kernel(const float* __restrict__ P,
                                   unsigned short* __restrict__ Out,
                                   size_t sSplit) {
    size_t i = ((size_t)blockIdx.x * blockDim.x + threadIdx.x) * 4;
    f32x4 s = *(const f32x4*)&P[i];
#pragma unroll
    for (int sp = 1; sp < NSPLIT; ++sp) {
        f32x4 t = *(const f32x4*)&P[(size_t)sp * sSplit + i];
        s = s + t;
    }
    u16x4 u;
    u[0] = f2bf(s[0]); u[1] = f2bf(s[1]); u[2] = f2bf(s[2]); u[3] = f2bf(s[3]);
    *(u16x4*)&Out[i] = u;
}

// C[M,N] = A[M,K] @ Bt[N,K]^T  (bf16 in, fp32 accum, OutT out)
// 128x128 tile, BK=64, 256 threads (4 waves), each wave 64x64 via 4x4 frags
// of v_mfma_f32_16x16x32_bf16. LDS layout fragment-major [BK/8][128][8].
// NSPLIT>1: blockIdx.z = bz*NSPLIT+sp, block computes K/NSPLIT slice into
// C + sSplit*sp (fp32 partials).
// Epilogue: round-1-validated scalar stores (16-lane x 4B = 64B segments).
// NOTE round-2 post-mortem: LDS-transpose epilogue via (float*)As type-pun
// produced absmax 5297 (TBAA reorder / intra-wave DS ordering hazard).
// Do not reintroduce without a dedicated float __shared__ buffer + barriers.
template <typename OutT, int NSPLIT>
__global__ __launch_bounds__(256, 2)
void gemm_bt_kernel(const unsigned short* __restrict__ A,
                    const unsigned short* __restrict__ Bt,
                    OutT* __restrict__ C,
                    int K, int lda, int ldb, int ldc,
                    size_t sA, size_t sB, size_t sC, size_t sSplit) {
    __shared__ __align__(16) unsigned short As[8192];
    __shared__ __align__(16) unsigned short Bs[8192];

    const int tid  = threadIdx.x;
    const int w    = tid >> 6;
    const int lane = tid & 63;
    const int wm   = w & 1;
    const int wn   = w >> 1;
    const int q    = lane >> 4;    // 0..3
    const int col  = lane & 15;

    const int tileN = blockIdx.x * 128;
    const int tileM = blockIdx.y * 128;
    const int bz    = blockIdx.z / NSPLIT;
    const int sp    = blockIdx.z % NSPLIT;
    const int Ksub  = K / NSPLIT;

    const unsigned short* Ab = A + sA * bz + (size_t)sp * Ksub;
    const unsigned short* Bb = Bt + sB * bz + (size_t)sp * Ksub;

    const unsigned short* gA[4];
    const unsigned short* gB[4];
    int ldsOff[4];
#pragma unroll
    for (int i = 0; i < 4; ++i) {
        int chunk = (w << 2) | i;              // 0..15, uniform per wave
        int m  = ((chunk & 1) << 6) | lane;    // 0..127
        int k8 = chunk >> 1;                   // 0..7
        gA[i] = Ab + (size_t)(tileM + m) * lda + k8 * 8;
        gB[i] = Bb + (size_t)(tileN + m) * ldb + k8 * 8;
        ldsOff[i] = chunk * 512;
    }

    f32x4 acc[4][4];
#pragma unroll
    for (int r = 0; r < 4; ++r)
#pragma unroll
        for (int c = 0; c < 4; ++c)
            acc[r][c] = (f32x4){0.f, 0.f, 0.f, 0.f};

    for (int k0 = 0; k0 < Ksub; k0 += 64) {
        __syncthreads();
#pragma unroll
        for (int i = 0; i < 4; ++i) {
            __builtin_amdgcn_global_load_lds(
                (const __attribute__((address_space(1))) void*)gA[i],
                (__attribute__((address_space(3))) void*)&As[ldsOff[i]],
                16, 0, 0);
            __builtin_amdgcn_global_load_lds(
                (const __attribute__((address_space(1))) void*)gB[i],
                (__attribute__((address_space(3))) void*)&Bs[ldsOff[i]],
                16, 0, 0);
            gA[i] += 64;
            gB[i] += 64;
        }
        __syncthreads();
#pragma unroll
        for (int kc = 0; kc < 2; ++kc) {       // kk = kc*32
            bf16x8 av[4], bv[4];
#pragma unroll
            for (int r = 0; r < 4; ++r)
                av[r] = *(const bf16x8*)&As[(((kc * 4 + q) * 128) + wm * 64 + r * 16 + col) * 8];
#pragma unroll
            for (int c = 0; c < 4; ++c)
                bv[c] = *(const bf16x8*)&Bs[(((kc * 4 + q) * 128) + wn * 64 + c * 16 + col) * 8];
#pragma unroll
            for (int r = 0; r < 4; ++r)
#pragma unroll
                for (int c = 0; c < 4; ++c)
                    acc[r][c] = __builtin_amdgcn_mfma_f32_16x16x32_bf16(
                        av[r], bv[c], acc[r][c], 0, 0, 0);
        }
    }

    OutT* Cb = C + sC * bz + sSplit * sp;
#pragma unroll
    for (int r = 0; r < 4; ++r) {
#pragma unroll
        for (int c = 0; c < 4; ++c) {
            int row0 = tileM + wm * 64 + r * 16 + q * 4;
            int colg = tileN + wn * 64 + c * 16 + col;
#pragma unroll
            for (int v = 0; v < 4; ++v) {
                float val = acc[r][c][v];
                if constexpr (sizeof(OutT) == 2) {
                    Cb[(size_t)(row0 + v) * ldc + colg] = (OutT)f2bf(val);
                } else {
                    Cb[(size_t)(row0 + v) * ldc + colg] = (OutT)val;
                }
            }
        }
    }
}

extern "C" void kernel_launch(void* const* d_in, const int* in_sizes, int n_in,
                              void* d_out, int out_size, void* d_ws, size_t ws_size,
                              hipStream_t stream) {
    const float* X = (const float*)d_in[0];   // [4,4096,1024]
    const float* W = (const float*)d_in[1];   // [1024,1024]
    float* out = (float*)d_out;               // [4,4096,1024] fp32

    char* ws = (char*)d_ws;
    unsigned short* Xb = (unsigned short*)(ws);              // 33,554,432  [b][s][h]
    unsigned short* XT = (unsigned short*)(ws + 33554432);   // 33,554,432  [b][h][s]
    unsigned short* WT = (unsigned short*)(ws + 67108864);   //  2,097,152  [h'][o]
    unsigned short* G  = (unsigned short*)(ws + 69206016);   //  8,388,608  [b][o][h]
    unsigned short* MT = (unsigned short*)(ws + 77594624);   //  8,388,608  [b][h''][h]
    float*       Gpart = (float*)(ws + 85983232);            // 67,108,864  [sp][b][1024*1024] fp32
    const size_t need_split = 85983232u + 67108864u;         // 153,092,096

    // 1) casts + transposes
    cast_x_kernel<<<dim3(H_DIM / 32, S_DIM / 32, B_DIM), dim3(32, 8), 0, stream>>>(X, Xb, XT);
    cast_w_kernel<<<dim3(H_DIM / 32, H_DIM / 32, 1), dim3(32, 8), 0, stream>>>(W, WT);

    if (ws_size >= need_split) {
        // 2) G_b = XT_b @ XT_b^T, split-K=4: 1024 blocks, fp32 partials
        gemm_bt_kernel<float, 4><<<dim3(8, 8, B_DIM * 4), 256, 0, stream>>>(
            XT, XT, Gpart, S_DIM, S_DIM, S_DIM, H_DIM,
            (size_t)H_DIM * S_DIM, (size_t)H_DIM * S_DIM,
            (size_t)H_DIM * H_DIM, (size_t)B_DIM * H_DIM * H_DIM);
        // 2b) reduce 4 partials -> bf16 G
        reduce_cast_kernel<4><<<dim3(B_DIM * H_DIM * H_DIM / 4 / 256), 256, 0, stream>>>(
            Gpart, G, (size_t)B_DIM * H_DIM * H_DIM);
    } else {
        gemm_bt_kernel<unsigned short, 1><<<dim3(8, 8, B_DIM), 256, 0, stream>>>(
            XT, XT, G, S_DIM, S_DIM, S_DIM, H_DIM,
            (size_t)H_DIM * S_DIM, (size_t)H_DIM * S_DIM, (size_t)H_DIM * H_DIM, 0);
    }

    // 3) MT_b = G_b @ WT^T  (= G W, valid since G symmetric)  [1024 x 1024], K = 1024
    gemm_bt_kernel<unsigned short, 1><<<dim3(8, 8, B_DIM), 256, 0, stream>>>(
        G, WT, MT, H_DIM, H_DIM, H_DIM, H_DIM,
        (size_t)H_DIM * H_DIM, (size_t)0, (size_t)H_DIM * H_DIM, 0);

    // 4) att_b = Xb_b @ MT_b^T   [4096 x 1024], K = 1024, fp32 out
    gemm_bt_kernel<float, 1><<<dim3(8, S_DIM / 128, B_DIM), 256, 0, stream>>>(
        Xb, MT, out, H_DIM, H_DIM, H_DIM, H_DIM,
        (size_t)S_DIM * H_DIM, (size_t)H_DIM * H_DIM, (size_t)S_DIM * H_DIM, 0);
}

// Round 4
// 301.632 us; speedup vs baseline: 1.1048x; 1.0605x over previous
//
#include <hip/hip_runtime.h>
#include <hip/hip_bf16.h>
#include <stdint.h>

#define H_DIM 1024
#define S_DIM 4096
#define B_DIM 4
#define NTRI 36   // 8x8 tile grid, lower triangle incl. diagonal

typedef __bf16 bf16x8 __attribute__((ext_vector_type(8)));
typedef float f32x4 __attribute__((ext_vector_type(4)));
typedef unsigned short u16x4 __attribute__((ext_vector_type(4)));

__device__ __forceinline__ unsigned short f2bf(float f) {
    union { float f; uint32_t u; } v; v.f = f;
    uint32_t u = v.u;
    uint32_t r = (u + 0x7FFFu + ((u >> 16) & 1u)) >> 16;  // round-to-nearest-even
    return (unsigned short)r;
}
__device__ __forceinline__ float bf2f(unsigned short u) {
    union { uint32_t u; float f; } v; v.u = (uint32_t)u << 16; return v.f;
}

// X[b][s][h] fp32 -> Xb[b][s][h] bf16  and  XT[b][h][s] bf16
__global__ void cast_x_kernel(const float* __restrict__ X,
                              unsigned short* __restrict__ Xb,
                              unsigned short* __restrict__ XT) {
    __shared__ float tile[32][33];
    const int b  = blockIdx.z;
    const int h0 = blockIdx.x * 32;
    const int s0 = blockIdx.y * 32;
    const int tx = threadIdx.x;   // 0..31
    const int ty = threadIdx.y;   // 0..7
    const float* src = X + ((size_t)b * S_DIM + s0) * H_DIM + h0;
#pragma unroll
    for (int i = 0; i < 4; ++i) {
        int s = ty + 8 * i;
        float v = src[(size_t)s * H_DIM + tx];
        tile[s][tx] = v;
        Xb[((size_t)b * S_DIM + s0 + s) * H_DIM + h0 + tx] = f2bf(v);
    }
    __syncthreads();
#pragma unroll
    for (int i = 0; i < 4; ++i) {
        int hh = ty + 8 * i;
        XT[((size_t)b * H_DIM + h0 + hh) * S_DIM + s0 + tx] = f2bf(tile[tx][hh]);
    }
}

// W[o][h'] fp32 -> WT[h'][o] bf16
__global__ void cast_w_kernel(const float* __restrict__ W,
                              unsigned short* __restrict__ WT) {
    __shared__ float tile[32][33];
    const int b0 = blockIdx.x * 32;   // cols of W (h')
    const int o0 = blockIdx.y * 32;   // rows of W (o)
    const int tx = threadIdx.x;
    const int ty = threadIdx.y;
#pragma unroll
    for (int i = 0; i < 4; ++i) {
        int o = ty + 8 * i;
        tile[o][tx] = W[(size_t)(o0 + o) * H_DIM + b0 + tx];
    }
    __syncthreads();
#pragma unroll
    for (int i = 0; i < 4; ++i) {
        int bb = ty + 8 * i;
        WT[(size_t)(b0 + bb) * H_DIM + o0 + tx] = f2bf(tile[tx][bb]);
    }
}

// Sum NSPLIT bf16 partials -> bf16. Plain elementwise (for MT).
template <int NSPLIT>
__global__ void reduce_cast_u16_kernel(const unsigned short* __restrict__ P,
                                       unsigned short* __restrict__ Out,
                                       size_t sSplit) {
    size_t i = ((size_t)blockIdx.x * blockDim.x + threadIdx.x) * 4;
    float s0 = 0.f, s1 = 0.f, s2 = 0.f, s3 = 0.f;
#pragma unroll
    for (int sp = 0; sp < NSPLIT; ++sp) {
        u16x4 u = *(const u16x4*)&P[(size_t)sp * sSplit + i];
        s0 += bf2f(u[0]); s1 += bf2f(u[1]); s2 += bf2f(u[2]); s3 += bf2f(u[3]);
    }
    u16x4 o;
    o[0] = f2bf(s0); o[1] = f2bf(s1); o[2] = f2bf(s2); o[3] = f2bf(s3);
    *(u16x4*)&Out[i] = o;
}

// Symmetric reduce for G: sum 8 bf16 partial tiles (lower-triangle tile list),
// write tile to G[ti][tj] and its transpose to G[tj][ti] via LDS (pad 129:
// phase-B column reads land 2-way on banks = free per m136). Diagonal tiles
// double-write bitwise-identical values (benign).
__global__ __launch_bounds__(256)
void reduce_sym_kernel(const unsigned short* __restrict__ P,
                       unsigned short* __restrict__ G) {
    __shared__ unsigned short t[128 * 129];
    const int tid  = threadIdx.x;
    const int tile = blockIdx.x;
    const int b    = blockIdx.y;
    int ti = 0;
    while ((ti + 1) * (ti + 2) / 2 <= tile) ++ti;
    const int tj = tile - ti * (ti + 1) / 2;
    unsigned short* Gb = G + (size_t)b * (H_DIM * H_DIM);
    const unsigned short* Pb = P + ((size_t)(b * 8) * NTRI + tile) * 16384;
#pragma unroll
    for (int it = 0; it < 16; ++it) {
        int i = it * 1024 + tid * 4;
        float s0 = 0.f, s1 = 0.f, s2 = 0.f, s3 = 0.f;
#pragma unroll
        for (int sp = 0; sp < 8; ++sp) {
            u16x4 u = *(const u16x4*)&Pb[(size_t)sp * (NTRI * 16384) + i];
            s0 += bf2f(u[0]); s1 += bf2f(u[1]); s2 += bf2f(u[2]); s3 += bf2f(u[3]);
        }
        u16x4 o;
        o[0] = f2bf(s0); o[1] = f2bf(s1); o[2] = f2bf(s2); o[3] = f2bf(s3);
        int r = i >> 7, c = i & 127;
        *(u16x4*)&Gb[(size_t)(ti * 128 + r) * H_DIM + tj * 128 + c] = o;
        t[r * 129 + c + 0] = o[0];
        t[r * 129 + c + 1] = o[1];
        t[r * 129 + c + 2] = o[2];
        t[r * 129 + c + 3] = o[3];
    }
    __syncthreads();
#pragma unroll
    for (int it = 0; it < 16; ++it) {
        int j = it * 1024 + tid * 4;
        int rr = j >> 7, cc = j & 127;
        u16x4 o;
        o[0] = t[(cc + 0) * 129 + rr];
        o[1] = t[(cc + 1) * 129 + rr];
        o[2] = t[(cc + 2) * 129 + rr];
        o[3] = t[(cc + 3) * 129 + rr];
        *(u16x4*)&Gb[(size_t)(tj * 128 + rr) * H_DIM + ti * 128 + cc] = o;
    }
}

// C[M,N] = A[M,K] @ Bt[N,K]^T  (bf16 in, fp32 accum, OutT out)
// 128x128 tile, BK=64, 256 threads (4 waves), each wave 64x64 via 4x4 frags
// of v_mfma_f32_16x16x32_bf16. LDS layout fragment-major [BK/8][128][8].
// NSPLIT>1: blockIdx.z = bz*NSPLIT+sp, K/NSPLIT slice per block.
// TRI: blockIdx.x = lower-triangle tile index (M==N==1024, 8x8 tiles);
//      output written tile-local to C + (blockIdx.z*NTRI + tileIdx)*16384.
// Epilogue: round-1-validated scalar stores. (R2 post-mortem: LDS-transpose
// epilogue via (float*)As type-pun corrupted output — don't reintroduce
// without a dedicated __shared__ buffer + barriers.)
template <typename OutT, int NSPLIT, bool TRI>
__global__ __launch_bounds__(256, 2)
void gemm_bt_kernel(const unsigned short* __restrict__ A,
                    const unsigned short* __restrict__ Bt,
                    OutT* __restrict__ C,
                    int K, int lda, int ldb, int ldc,
                    size_t sA, size_t sB, size_t sC, size_t sSplit) {
    __shared__ __align__(16) unsigned short As[8192];
    __shared__ __align__(16) unsigned short Bs[8192];

    const int tid  = threadIdx.x;
    const int w    = tid >> 6;
    const int lane = tid & 63;
    const int wm   = w & 1;
    const int wn   = w >> 1;
    const int q    = lane >> 4;    // 0..3
    const int col  = lane & 15;

    int tileM, tileN, tileIdx = 0;
    if constexpr (TRI) {
        tileIdx = (int)blockIdx.x;
        int ti = 0;
        while ((ti + 1) * (ti + 2) / 2 <= tileIdx) ++ti;
        int tj = tileIdx - ti * (ti + 1) / 2;
        tileM = ti * 128;
        tileN = tj * 128;
    } else {
        tileN = blockIdx.x * 128;
        tileM = blockIdx.y * 128;
    }
    const int bz   = blockIdx.z / NSPLIT;
    const int sp   = blockIdx.z % NSPLIT;
    const int Ksub = K / NSPLIT;

    const unsigned short* Ab = A + sA * bz + (size_t)sp * Ksub;
    const unsigned short* Bb = Bt + sB * bz + (size_t)sp * Ksub;

    const unsigned short* gA[4];
    const unsigned short* gB[4];
    int ldsOff[4];
#pragma unroll
    for (int i = 0; i < 4; ++i) {
        int chunk = (w << 2) | i;              // 0..15, uniform per wave
        int m  = ((chunk & 1) << 6) | lane;    // 0..127
        int k8 = chunk >> 1;                   // 0..7
        gA[i] = Ab + (size_t)(tileM + m) * lda + k8 * 8;
        gB[i] = Bb + (size_t)(tileN + m) * ldb + k8 * 8;
        ldsOff[i] = chunk * 512;
    }

    f32x4 acc[4][4];
#pragma unroll
    for (int r = 0; r < 4; ++r)
#pragma unroll
        for (int c = 0; c < 4; ++c)
            acc[r][c] = (f32x4){0.f, 0.f, 0.f, 0.f};

    for (int k0 = 0; k0 < Ksub; k0 += 64) {
        __syncthreads();
#pragma unroll
        for (int i = 0; i < 4; ++i) {
            __builtin_amdgcn_global_load_lds(
                (const __attribute__((address_space(1))) void*)gA[i],
                (__attribute__((address_space(3))) void*)&As[ldsOff[i]],
                16, 0, 0);
            __builtin_amdgcn_global_load_lds(
                (const __attribute__((address_space(1))) void*)gB[i],
                (__attribute__((address_space(3))) void*)&Bs[ldsOff[i]],
                16, 0, 0);
            gA[i] += 64;
            gB[i] += 64;
        }
        __syncthreads();
#pragma unroll
        for (int kc = 0; kc < 2; ++kc) {       // kk = kc*32
            bf16x8 av[4], bv[4];
#pragma unroll
            for (int r = 0; r < 4; ++r)
                av[r] = *(const bf16x8*)&As[(((kc * 4 + q) * 128) + wm * 64 + r * 16 + col) * 8];
#pragma unroll
            for (int c = 0; c < 4; ++c)
                bv[c] = *(const bf16x8*)&Bs[(((kc * 4 + q) * 128) + wn * 64 + c * 16 + col) * 8];
#pragma unroll
            for (int r = 0; r < 4; ++r)
#pragma unroll
                for (int c = 0; c < 4; ++c)
                    acc[r][c] = __builtin_amdgcn_mfma_f32_16x16x32_bf16(
                        av[r], bv[c], acc[r][c], 0, 0, 0);
        }
    }

    OutT* Cb;
    int ldcl, rowBase, colBase;
    if constexpr (TRI) {
        Cb = C + ((size_t)blockIdx.z * NTRI + tileIdx) * 16384;
        ldcl = 128; rowBase = 0; colBase = 0;
    } else {
        Cb = C + sC * bz + sSplit * sp;
        ldcl = ldc; rowBase = tileM; colBase = tileN;
    }
#pragma unroll
    for (int r = 0; r < 4; ++r) {
#pragma unroll
        for (int c = 0; c < 4; ++c) {
            int row0 = rowBase + wm * 64 + r * 16 + q * 4;
            int colg = colBase + wn * 64 + c * 16 + col;
#pragma unroll
            for (int v = 0; v < 4; ++v) {
                float val = acc[r][c][v];
                if constexpr (sizeof(OutT) == 2) {
                    Cb[(size_t)(row0 + v) * ldcl + colg] = (OutT)f2bf(val);
                } else {
                    Cb[(size_t)(row0 + v) * ldcl + colg] = (OutT)val;
                }
            }
        }
    }
}

extern "C" void kernel_launch(void* const* d_in, const int* in_sizes, int n_in,
                              void* d_out, int out_size, void* d_ws, size_t ws_size,
                              hipStream_t stream) {
    const float* X = (const float*)d_in[0];   // [4,4096,1024]
    const float* W = (const float*)d_in[1];   // [1024,1024]
    float* out = (float*)d_out;               // [4,4096,1024] fp32

    char* ws = (char*)d_ws;
    unsigned short* Xb = (unsigned short*)(ws);              // 33,554,432  [b][s][h]
    unsigned short* XT = (unsigned short*)(ws + 33554432);   // 33,554,432  [b][h][s]
    unsigned short* WT = (unsigned short*)(ws + 67108864);   //  2,097,152  [h'][o]
    unsigned short* G  = (unsigned short*)(ws + 69206016);   //  8,388,608  [b][o][h]
    unsigned short* MT = (unsigned short*)(ws + 77594624);   //  8,388,608  [b][h''][h]
    // Scratch region (reused serially): G partials then MT partials.
    unsigned short* Gpart  = (unsigned short*)(ws + 85983232); // 36*32*16384*2 = 37,748,736
    unsigned short* MTpart = (unsigned short*)(ws + 85983232); // 4*4*1M*2     = 33,554,432
    // high-water: 123,731,968 bytes < 153,092,096 proven available (R3)

    // 1) casts + transposes
    cast_x_kernel<<<dim3(H_DIM / 32, S_DIM / 32, B_DIM), dim3(32, 8), 0, stream>>>(X, Xb, XT);
    cast_w_kernel<<<dim3(H_DIM / 32, H_DIM / 32, 1), dim3(32, 8), 0, stream>>>(W, WT);

    // 2) G_b = XT_b @ XT_b^T, symmetric: 36 lower-tri tiles, split-K=8, bf16 partials
    gemm_bt_kernel<unsigned short, 8, true><<<dim3(NTRI, 1, B_DIM * 8), 256, 0, stream>>>(
        XT, XT, Gpart, S_DIM, S_DIM, S_DIM, 128,
        (size_t)H_DIM * S_DIM, (size_t)H_DIM * S_DIM, 0, 0);
    // 2b) reduce partials + mirror transpose -> bf16 G (full)
    reduce_sym_kernel<<<dim3(NTRI, B_DIM), 256, 0, stream>>>(Gpart, G);

    // 3) MT_b = G_b @ WT^T (= G W, G symmetric), split-K=4, bf16 partials
    gemm_bt_kernel<unsigned short, 4, false><<<dim3(8, 8, B_DIM * 4), 256, 0, stream>>>(
        G, WT, MTpart, H_DIM, H_DIM, H_DIM, H_DIM,
        (size_t)H_DIM * H_DIM, (size_t)0, (size_t)H_DIM * H_DIM,
        (size_t)B_DIM * H_DIM * H_DIM);
    reduce_cast_u16_kernel<4><<<dim3(B_DIM * H_DIM * H_DIM / 4 / 256), 256, 0, stream>>>(
        MTpart, MT, (size_t)B_DIM * H_DIM * H_DIM);

    // 4) att_b = Xb_b @ MT_b^T   [4096 x 1024], K = 1024, fp32 out
    gemm_bt_kernel<float, 1, false><<<dim3(8, S_DIM / 128, B_DIM), 256, 0, stream>>>(
        Xb, MT, out, H_DIM, H_DIM, H_DIM, H_DIM,
        (size_t)S_DIM * H_DIM, (size_t)H_DIM * H_DIM, (size_t)S_DIM * H_DIM, 0);
}

// Round 5
// 292.272 us; speedup vs baseline: 1.1402x; 1.0320x over previous
//
#include <hip/hip_runtime.h>
#include <hip/hip_bf16.h>
#include <stdint.h>

#define H_DIM 1024
#define S_DIM 4096
#define B_DIM 4
#define NTRI 36   // 8x8 tile grid, lower triangle incl. diagonal

typedef __bf16 bf16x8 __attribute__((ext_vector_type(8)));
typedef float f32x4 __attribute__((ext_vector_type(4)));
typedef unsigned short u16x4 __attribute__((ext_vector_type(4)));

__device__ __forceinline__ unsigned short f2bf(float f) {
    union { float f; uint32_t u; } v; v.f = f;
    uint32_t u = v.u;
    uint32_t r = (u + 0x7FFFu + ((u >> 16) & 1u)) >> 16;  // round-to-nearest-even
    return (unsigned short)r;
}
__device__ __forceinline__ float bf2f(unsigned short u) {
    union { uint32_t u; float f; } v; v.u = (uint32_t)u << 16; return v.f;
}

// X[b][s][h] fp32 -> Xb[b][s][h] bf16  and  XT[b][h][s] bf16
__global__ void cast_x_kernel(const float* __restrict__ X,
                              unsigned short* __restrict__ Xb,
                              unsigned short* __restrict__ XT) {
    __shared__ float tile[32][33];
    const int b  = blockIdx.z;
    const int h0 = blockIdx.x * 32;
    const int s0 = blockIdx.y * 32;
    const int tx = threadIdx.x;   // 0..31
    const int ty = threadIdx.y;   // 0..7
    const float* src = X + ((size_t)b * S_DIM + s0) * H_DIM + h0;
#pragma unroll
    for (int i = 0; i < 4; ++i) {
        int s = ty + 8 * i;
        float v = src[(size_t)s * H_DIM + tx];
        tile[s][tx] = v;
        Xb[((size_t)b * S_DIM + s0 + s) * H_DIM + h0 + tx] = f2bf(v);
    }
    __syncthreads();
#pragma unroll
    for (int i = 0; i < 4; ++i) {
        int hh = ty + 8 * i;
        XT[((size_t)b * H_DIM + h0 + hh) * S_DIM + s0 + tx] = f2bf(tile[tx][hh]);
    }
}

// W[o][h'] fp32 -> WT[h'][o] bf16
__global__ void cast_w_kernel(const float* __restrict__ W,
                              unsigned short* __restrict__ WT) {
    __shared__ float tile[32][33];
    const int b0 = blockIdx.x * 32;   // cols of W (h')
    const int o0 = blockIdx.y * 32;   // rows of W (o)
    const int tx = threadIdx.x;
    const int ty = threadIdx.y;
#pragma unroll
    for (int i = 0; i < 4; ++i) {
        int o = ty + 8 * i;
        tile[o][tx] = W[(size_t)(o0 + o) * H_DIM + b0 + tx];
    }
    __syncthreads();
#pragma unroll
    for (int i = 0; i < 4; ++i) {
        int bb = ty + 8 * i;
        WT[(size_t)(b0 + bb) * H_DIM + o0 + tx] = f2bf(tile[tx][bb]);
    }
}

// Sum NSPLIT bf16 partials -> bf16. Plain elementwise (for MT).
template <int NSPLIT>
__global__ void reduce_cast_u16_kernel(const unsigned short* __restrict__ P,
                                       unsigned short* __restrict__ Out,
                                       size_t sSplit) {
    size_t i = ((size_t)blockIdx.x * blockDim.x + threadIdx.x) * 4;
    float s0 = 0.f, s1 = 0.f, s2 = 0.f, s3 = 0.f;
#pragma unroll
    for (int sp = 0; sp < NSPLIT; ++sp) {
        u16x4 u = *(const u16x4*)&P[(size_t)sp * sSplit + i];
        s0 += bf2f(u[0]); s1 += bf2f(u[1]); s2 += bf2f(u[2]); s3 += bf2f(u[3]);
    }
    u16x4 o;
    o[0] = f2bf(s0); o[1] = f2bf(s1); o[2] = f2bf(s2); o[3] = f2bf(s3);
    *(u16x4*)&Out[i] = o;
}

// Symmetric reduce for G: sum 8 bf16 partial tiles (lower-triangle tile list),
// write tile to G[ti][tj] and its transpose to G[tj][ti] via LDS (pad 129).
// Diagonal tiles double-write bitwise-identical values (benign).
__global__ __launch_bounds__(256)
void reduce_sym_kernel(const unsigned short* __restrict__ P,
                       unsigned short* __restrict__ G) {
    __shared__ unsigned short t[128 * 129];
    const int tid  = threadIdx.x;
    const int tile = blockIdx.x;
    const int b    = blockIdx.y;
    int ti = 0;
    while ((ti + 1) * (ti + 2) / 2 <= tile) ++ti;
    const int tj = tile - ti * (ti + 1) / 2;
    unsigned short* Gb = G + (size_t)b * (H_DIM * H_DIM);
    const unsigned short* Pb = P + ((size_t)(b * 8) * NTRI + tile) * 16384;
#pragma unroll
    for (int it = 0; it < 16; ++it) {
        int i = it * 1024 + tid * 4;
        float s0 = 0.f, s1 = 0.f, s2 = 0.f, s3 = 0.f;
#pragma unroll
        for (int sp = 0; sp < 8; ++sp) {
            u16x4 u = *(const u16x4*)&Pb[(size_t)sp * (NTRI * 16384) + i];
            s0 += bf2f(u[0]); s1 += bf2f(u[1]); s2 += bf2f(u[2]); s3 += bf2f(u[3]);
        }
        u16x4 o;
        o[0] = f2bf(s0); o[1] = f2bf(s1); o[2] = f2bf(s2); o[3] = f2bf(s3);
        int r = i >> 7, c = i & 127;
        *(u16x4*)&Gb[(size_t)(ti * 128 + r) * H_DIM + tj * 128 + c] = o;
        t[r * 129 + c + 0] = o[0];
        t[r * 129 + c + 1] = o[1];
        t[r * 129 + c + 2] = o[2];
        t[r * 129 + c + 3] = o[3];
    }
    __syncthreads();
#pragma unroll
    for (int it = 0; it < 16; ++it) {
        int j = it * 1024 + tid * 4;
        int rr = j >> 7, cc = j & 127;
        u16x4 o;
        o[0] = t[(cc + 0) * 129 + rr];
        o[1] = t[(cc + 1) * 129 + rr];
        o[2] = t[(cc + 2) * 129 + rr];
        o[3] = t[(cc + 3) * 129 + rr];
        *(u16x4*)&Gb[(size_t)(tj * 128 + rr) * H_DIM + ti * 128 + cc] = o;
    }
}

// C[M,N] = A[M,K] @ Bt[N,K]^T  (bf16 in, fp32 accum, OutT out)
// 128x128 tile, BK=64, 256 threads (4 waves), 4x4 frags of
// v_mfma_f32_16x16x32_bf16. LDS fragment-major [BK/8][128][8].
// NSPLIT>1: blockIdx.z = bz*NSPLIT+sp, K/NSPLIT slice per block.
// TRI: blockIdx.x = lower-triangle tile index, tile-local output.
// SWAPXY: blockIdx.x = M-tile, y = N-tile (XCD swizzle: A-tile sharers sit
// 32 apart in linear id == same XCD under round-robin -> A fetched once).
// Epilogue: per-wave LDS transpose through a UNION-typed f32 view of As with
// explicit __syncthreads between phases (fixes both R2 failure mechanisms:
// type-punned TBAA reorder + missing write->read ordering).
template <typename OutT, int NSPLIT, bool TRI, bool SWAPXY>
__global__ __launch_bounds__(256, 2)
void gemm_bt_kernel(const unsigned short* __restrict__ A,
                    const unsigned short* __restrict__ Bt,
                    OutT* __restrict__ C,
                    int K, int lda, int ldb, int ldc,
                    size_t sA, size_t sB, size_t sC, size_t sSplit) {
    __shared__ __align__(16) union ShU { unsigned short u16[8192]; float f32[4096]; } As, Bs;

    const int tid  = threadIdx.x;
    const int w    = tid >> 6;
    const int lane = tid & 63;
    const int wm   = w & 1;
    const int wn   = w >> 1;
    const int q    = lane >> 4;    // 0..3
    const int col  = lane & 15;

    int tileM, tileN, tileIdx = 0;
    if constexpr (TRI) {
        tileIdx = (int)blockIdx.x;
        int ti = 0;
        while ((ti + 1) * (ti + 2) / 2 <= tileIdx) ++ti;
        int tj = tileIdx - ti * (ti + 1) / 2;
        tileM = ti * 128;
        tileN = tj * 128;
    } else if constexpr (SWAPXY) {
        tileM = blockIdx.x * 128;
        tileN = blockIdx.y * 128;
    } else {
        tileN = blockIdx.x * 128;
        tileM = blockIdx.y * 128;
    }
    const int bz   = blockIdx.z / NSPLIT;
    const int sp   = blockIdx.z % NSPLIT;
    const int Ksub = K / NSPLIT;

    const unsigned short* Ab = A + sA * bz + (size_t)sp * Ksub;
    const unsigned short* Bb = Bt + sB * bz + (size_t)sp * Ksub;

    const unsigned short* gA[4];
    const unsigned short* gB[4];
    int ldsOff[4];
#pragma unroll
    for (int i = 0; i < 4; ++i) {
        int chunk = (w << 2) | i;              // 0..15, uniform per wave
        int m  = ((chunk & 1) << 6) | lane;    // 0..127
        int k8 = chunk >> 1;                   // 0..7
        gA[i] = Ab + (size_t)(tileM + m) * lda + k8 * 8;
        gB[i] = Bb + (size_t)(tileN + m) * ldb + k8 * 8;
        ldsOff[i] = chunk * 512;
    }

    f32x4 acc[4][4];
#pragma unroll
    for (int r = 0; r < 4; ++r)
#pragma unroll
        for (int c = 0; c < 4; ++c)
            acc[r][c] = (f32x4){0.f, 0.f, 0.f, 0.f};

    for (int k0 = 0; k0 < Ksub; k0 += 64) {
        __syncthreads();
#pragma unroll
        for (int i = 0; i < 4; ++i) {
            __builtin_amdgcn_global_load_lds(
                (const __attribute__((address_space(1))) void*)gA[i],
                (__attribute__((address_space(3))) void*)&As.u16[ldsOff[i]],
                16, 0, 0);
            __builtin_amdgcn_global_load_lds(
                (const __attribute__((address_space(1))) void*)gB[i],
                (__attribute__((address_space(3))) void*)&Bs.u16[ldsOff[i]],
                16, 0, 0);
            gA[i] += 64;
            gB[i] += 64;
        }
        __syncthreads();
#pragma unroll
        for (int kc = 0; kc < 2; ++kc) {       // kk = kc*32
            bf16x8 av[4], bv[4];
#pragma unroll
            for (int r = 0; r < 4; ++r)
                av[r] = *(const bf16x8*)&As.u16[(((kc * 4 + q) * 128) + wm * 64 + r * 16 + col) * 8];
#pragma unroll
            for (int c = 0; c < 4; ++c)
                bv[c] = *(const bf16x8*)&Bs.u16[(((kc * 4 + q) * 128) + wn * 64 + c * 16 + col) * 8];
#pragma unroll
            for (int r = 0; r < 4; ++r)
#pragma unroll
                for (int c = 0; c < 4; ++c)
                    acc[r][c] = __builtin_amdgcn_mfma_f32_16x16x32_bf16(
                        av[r], bv[c], acc[r][c], 0, 0, 0);
        }
    }

    OutT* Cb;
    int ldcl, rowBase, colBase;
    if constexpr (TRI) {
        Cb = C + ((size_t)blockIdx.z * NTRI + tileIdx) * 16384;
        ldcl = 128; rowBase = 0; colBase = 0;
    } else {
        Cb = C + sC * bz + sSplit * sp;
        ldcl = ldc; rowBase = tileM; colBase = tileN;
    }

    // vectorized epilogue: per-wave 4KB f32 slice of As, phase-barriered
    float* lws = As.f32 + w * 1024;
    const int lr = lane >> 4;      // 0..3
    const int lc = lane & 15;      // 0..15
#pragma unroll
    for (int r = 0; r < 4; ++r) {
        __syncthreads();   // r=0: K-loop LDS reads done; r>0: prev read phase done
#pragma unroll
        for (int c = 0; c < 4; ++c)
#pragma unroll
            for (int v = 0; v < 4; ++v)
                lws[(q * 4 + v) * 64 + c * 16 + col] = acc[r][c][v];
        __syncthreads();   // write phase visible before read phase
#pragma unroll
        for (int p = 0; p < 4; ++p) {
            f32x4 t = *(const f32x4*)&lws[(p * 4 + lr) * 64 + lc * 4];
            int row  = rowBase + wm * 64 + r * 16 + p * 4 + lr;
            int colg = colBase + wn * 64 + lc * 4;
            if constexpr (sizeof(OutT) == 2) {
                u16x4 u;
                u[0] = f2bf(t[0]); u[1] = f2bf(t[1]);
                u[2] = f2bf(t[2]); u[3] = f2bf(t[3]);
                *(u16x4*)&Cb[(size_t)row * ldcl + colg] = u;
            } else {
                *(f32x4*)&Cb[(size_t)row * ldcl + colg] = t;
            }
        }
    }
}

extern "C" void kernel_launch(void* const* d_in, const int* in_sizes, int n_in,
                              void* d_out, int out_size, void* d_ws, size_t ws_size,
                              hipStream_t stream) {
    const float* X = (const float*)d_in[0];   // [4,4096,1024]
    const float* W = (const float*)d_in[1];   // [1024,1024]
    float* out = (float*)d_out;               // [4,4096,1024] fp32

    char* ws = (char*)d_ws;
    unsigned short* Xb = (unsigned short*)(ws);              // 33,554,432  [b][s][h]
    unsigned short* XT = (unsigned short*)(ws + 33554432);   // 33,554,432  [b][h][s]
    unsigned short* WT = (unsigned short*)(ws + 67108864);   //  2,097,152  [h'][o]
    unsigned short* G  = (unsigned short*)(ws + 69206016);   //  8,388,608  [b][o][h]
    unsigned short* MT = (unsigned short*)(ws + 77594624);   //  8,388,608  [b][h''][h]
    // Scratch region (reused serially): G partials then MT partials.
    unsigned short* Gpart  = (unsigned short*)(ws + 85983232); // 36*32*16384*2 = 37,748,736
    unsigned short* MTpart = (unsigned short*)(ws + 85983232); // 4*4*1M*2     = 33,554,432
    // high-water: 123,731,968 bytes < 153,092,096 proven available (R3)

    // 1) casts + transposes
    cast_x_kernel<<<dim3(H_DIM / 32, S_DIM / 32, B_DIM), dim3(32, 8), 0, stream>>>(X, Xb, XT);
    cast_w_kernel<<<dim3(H_DIM / 32, H_DIM / 32, 1), dim3(32, 8), 0, stream>>>(W, WT);

    // 2) G_b = XT_b @ XT_b^T, symmetric: 36 lower-tri tiles, split-K=8, bf16 partials
    gemm_bt_kernel<unsigned short, 8, true, false><<<dim3(NTRI, 1, B_DIM * 8), 256, 0, stream>>>(
        XT, XT, Gpart, S_DIM, S_DIM, S_DIM, 128,
        (size_t)H_DIM * S_DIM, (size_t)H_DIM * S_DIM, 0, 0);
    // 2b) reduce partials + mirror transpose -> bf16 G (full)
    reduce_sym_kernel<<<dim3(NTRI, B_DIM), 256, 0, stream>>>(Gpart, G);

    // 3) MT_b = G_b @ WT^T (= G W, G symmetric), split-K=4, bf16 partials
    gemm_bt_kernel<unsigned short, 4, false, false><<<dim3(8, 8, B_DIM * 4), 256, 0, stream>>>(
        G, WT, MTpart, H_DIM, H_DIM, H_DIM, H_DIM,
        (size_t)H_DIM * H_DIM, (size_t)0, (size_t)H_DIM * H_DIM,
        (size_t)B_DIM * H_DIM * H_DIM);
    reduce_cast_u16_kernel<4><<<dim3(B_DIM * H_DIM * H_DIM / 4 / 256), 256, 0, stream>>>(
        MTpart, MT, (size_t)B_DIM * H_DIM * H_DIM);

    // 4) att_b = Xb_b @ MT_b^T   [4096 x 1024], K = 1024, fp32 out
    //    SWAPXY: x = M-tile (32), y = N-tile (8) -> A-tile sharers 32 apart
    //    in linear id (same XCD mod 8); grid fully co-resident (4 blocks/CU).
    gemm_bt_kernel<float, 1, false, true><<<dim3(S_DIM / 128, 8, B_DIM), 256, 0, stream>>>(
        Xb, MT, out, H_DIM, H_DIM, H_DIM, H_DIM,
        (size_t)S_DIM * H_DIM, (size_t)H_DIM * H_DIM, (size_t)S_DIM * H_DIM, 0);
}

// Round 6
// 286.500 us; speedup vs baseline: 1.1632x; 1.0201x over previous
//
#include <hip/hip_runtime.h>
#include <hip/hip_bf16.h>
#include <stdint.h>

#define H_DIM 1024
#define S_DIM 4096
#define B_DIM 4
#define NTRI 36   // 8x8 tile grid, lower triangle incl. diagonal

typedef __bf16 bf16x8 __attribute__((ext_vector_type(8)));
typedef float f32x4 __attribute__((ext_vector_type(4)));
typedef unsigned short u16x4 __attribute__((ext_vector_type(4)));

__device__ __forceinline__ unsigned short f2bf(float f) {
    union { float f; uint32_t u; } v; v.f = f;
    uint32_t u = v.u;
    uint32_t r = (u + 0x7FFFu + ((u >> 16) & 1u)) >> 16;  // round-to-nearest-even
    return (unsigned short)r;
}
__device__ __forceinline__ float bf2f(unsigned short u) {
    union { uint32_t u; float f; } v; v.u = (uint32_t)u << 16; return v.f;
}

// X[b][s][h] fp32 -> Xb[b][s][h] bf16  and  XT[b][h][s] bf16
__global__ void cast_x_kernel(const float* __restrict__ X,
                              unsigned short* __restrict__ Xb,
                              unsigned short* __restrict__ XT) {
    __shared__ float tile[32][33];
    const int b  = blockIdx.z;
    const int h0 = blockIdx.x * 32;
    const int s0 = blockIdx.y * 32;
    const int tx = threadIdx.x;   // 0..31
    const int ty = threadIdx.y;   // 0..7
    const float* src = X + ((size_t)b * S_DIM + s0) * H_DIM + h0;
#pragma unroll
    for (int i = 0; i < 4; ++i) {
        int s = ty + 8 * i;
        float v = src[(size_t)s * H_DIM + tx];
        tile[s][tx] = v;
        Xb[((size_t)b * S_DIM + s0 + s) * H_DIM + h0 + tx] = f2bf(v);
    }
    __syncthreads();
#pragma unroll
    for (int i = 0; i < 4; ++i) {
        int hh = ty + 8 * i;
        XT[((size_t)b * H_DIM + h0 + hh) * S_DIM + s0 + tx] = f2bf(tile[tx][hh]);
    }
}

// W[o][h'] fp32 -> WT[h'][o] bf16
__global__ void cast_w_kernel(const float* __restrict__ W,
                              unsigned short* __restrict__ WT) {
    __shared__ float tile[32][33];
    const int b0 = blockIdx.x * 32;   // cols of W (h')
    const int o0 = blockIdx.y * 32;   // rows of W (o)
    const int tx = threadIdx.x;
    const int ty = threadIdx.y;
#pragma unroll
    for (int i = 0; i < 4; ++i) {
        int o = ty + 8 * i;
        tile[o][tx] = W[(size_t)(o0 + o) * H_DIM + b0 + tx];
    }
    __syncthreads();
#pragma unroll
    for (int i = 0; i < 4; ++i) {
        int bb = ty + 8 * i;
        WT[(size_t)(b0 + bb) * H_DIM + o0 + tx] = f2bf(tile[tx][bb]);
    }
}

// Sum NSPLIT bf16 partials -> bf16. Plain elementwise (for MT).
template <int NSPLIT>
__global__ void reduce_cast_u16_kernel(const unsigned short* __restrict__ P,
                                       unsigned short* __restrict__ Out,
                                       size_t sSplit) {
    size_t i = ((size_t)blockIdx.x * blockDim.x + threadIdx.x) * 4;
    float s0 = 0.f, s1 = 0.f, s2 = 0.f, s3 = 0.f;
#pragma unroll
    for (int sp = 0; sp < NSPLIT; ++sp) {
        u16x4 u = *(const u16x4*)&P[(size_t)sp * sSplit + i];
        s0 += bf2f(u[0]); s1 += bf2f(u[1]); s2 += bf2f(u[2]); s3 += bf2f(u[3]);
    }
    u16x4 o;
    o[0] = f2bf(s0); o[1] = f2bf(s1); o[2] = f2bf(s2); o[3] = f2bf(s3);
    *(u16x4*)&Out[i] = o;
}

// Symmetric reduce for G: sum NS bf16 partial tiles (lower-triangle list),
// write tile to G[ti][tj] and transpose to G[tj][ti] via LDS (pad 129).
// Diagonal tiles double-write bitwise-identical values (benign).
template <int NS>
__global__ __launch_bounds__(256)
void reduce_sym_kernel(const unsigned short* __restrict__ P,
                       unsigned short* __restrict__ G) {
    __shared__ unsigned short t[128 * 129];
    const int tid  = threadIdx.x;
    const int tile = blockIdx.x;
    const int b    = blockIdx.y;
    int ti = 0;
    while ((ti + 1) * (ti + 2) / 2 <= tile) ++ti;
    const int tj = tile - ti * (ti + 1) / 2;
    unsigned short* Gb = G + (size_t)b * (H_DIM * H_DIM);
    const unsigned short* Pb = P + ((size_t)(b * NS) * NTRI + tile) * 16384;
#pragma unroll
    for (int it = 0; it < 16; ++it) {
        int i = it * 1024 + tid * 4;
        float s0 = 0.f, s1 = 0.f, s2 = 0.f, s3 = 0.f;
#pragma unroll
        for (int sp = 0; sp < NS; ++sp) {
            u16x4 u = *(const u16x4*)&Pb[(size_t)sp * (NTRI * 16384) + i];
            s0 += bf2f(u[0]); s1 += bf2f(u[1]); s2 += bf2f(u[2]); s3 += bf2f(u[3]);
        }
        u16x4 o;
        o[0] = f2bf(s0); o[1] = f2bf(s1); o[2] = f2bf(s2); o[3] = f2bf(s3);
        int r = i >> 7, c = i & 127;
        *(u16x4*)&Gb[(size_t)(ti * 128 + r) * H_DIM + tj * 128 + c] = o;
        t[r * 129 + c + 0] = o[0];
        t[r * 129 + c + 1] = o[1];
        t[r * 129 + c + 2] = o[2];
        t[r * 129 + c + 3] = o[3];
    }
    __syncthreads();
#pragma unroll
    for (int it = 0; it < 16; ++it) {
        int j = it * 1024 + tid * 4;
        int rr = j >> 7, cc = j & 127;
        u16x4 o;
        o[0] = t[(cc + 0) * 129 + rr];
        o[1] = t[(cc + 1) * 129 + rr];
        o[2] = t[(cc + 2) * 129 + rr];
        o[3] = t[(cc + 3) * 129 + rr];
        *(u16x4*)&Gb[(size_t)(tj * 128 + rr) * H_DIM + ti * 128 + cc] = o;
    }
}

// C[M,N] = A[M,K] @ Bt[N,K]^T  (bf16 in, fp32 accum, OutT out)
// 128x128 tile, BK=64, 256 threads (4 waves), 4x4 frags of
// v_mfma_f32_16x16x32_bf16. LDS fragment-major [BK/8][128][8].
// DOUBLE-BUFFERED K-loop (one barrier/iter): loads for tile t+1 issue before
// compute of tile t, so each barrier's vmcnt drain waits on loads that had a
// full compute phase in flight (attacks the R5-measured latency stall:
// MfmaUtil 17.5 / VALU 8.6 / HBM 19% = 75% idle on barrier drains).
// LDS 64KB -> 2 blocks/CU (traded from 4; dbuf hiding must beat it).
// NSPLIT>1: blockIdx.z = bz*NSPLIT+sp, K/NSPLIT slice per block.
// TRI: blockIdx.x = lower-triangle tile index, tile-local output.
// SWAPXY: x = M-tile, y = N-tile (XCD swizzle; R5: FETCH 137->49 MB).
// Epilogue: per-wave LDS transpose, stride 68 floats (write phase 2-way).
template <typename OutT, int NSPLIT, bool TRI, bool SWAPXY>
__global__ __launch_bounds__(256, 2)
void gemm_bt_kernel(const unsigned short* __restrict__ A,
                    const unsigned short* __restrict__ Bt,
                    OutT* __restrict__ C,
                    int K, int lda, int ldb, int ldc,
                    size_t sA, size_t sB, size_t sC, size_t sSplit) {
    __shared__ __align__(16) union Sh {
        unsigned short stage[2][2][8192];   // [buf][A=0/B=1][frag-major tile]
        float epi[4][1088];                 // epilogue: 16 rows x stride 68 / wave
    } sh;

    const int tid  = threadIdx.x;
    const int w    = tid >> 6;
    const int lane = tid & 63;
    const int wm   = w & 1;
    const int wn   = w >> 1;
    const int q    = lane >> 4;    // 0..3
    const int col  = lane & 15;

    int tileM, tileN, tileIdx = 0;
    if constexpr (TRI) {
        tileIdx = (int)blockIdx.x;
        int ti = 0;
        while ((ti + 1) * (ti + 2) / 2 <= tileIdx) ++ti;
        int tj = tileIdx - ti * (ti + 1) / 2;
        tileM = ti * 128;
        tileN = tj * 128;
    } else if constexpr (SWAPXY) {
        tileM = blockIdx.x * 128;
        tileN = blockIdx.y * 128;
    } else {
        tileN = blockIdx.x * 128;
        tileM = blockIdx.y * 128;
    }
    const int bz   = blockIdx.z / NSPLIT;
    const int sp   = blockIdx.z % NSPLIT;
    const int Ksub = K / NSPLIT;

    const unsigned short* Ab = A + sA * bz + (size_t)sp * Ksub;
    const unsigned short* Bb = Bt + sB * bz + (size_t)sp * Ksub;

    const unsigned short* gA[4];
    const unsigned short* gB[4];
    int ldsOff[4];
#pragma unroll
    for (int i = 0; i < 4; ++i) {
        int chunk = (w << 2) | i;              // 0..15, uniform per wave
        int m  = ((chunk & 1) << 6) | lane;    // 0..127
        int k8 = chunk >> 1;                   // 0..7
        gA[i] = Ab + (size_t)(tileM + m) * lda + k8 * 8;
        gB[i] = Bb + (size_t)(tileN + m) * ldb + k8 * 8;
        ldsOff[i] = chunk * 512;
    }

    f32x4 acc[4][4];
#pragma unroll
    for (int r = 0; r < 4; ++r)
#pragma unroll
        for (int c = 0; c < 4; ++c)
            acc[r][c] = (f32x4){0.f, 0.f, 0.f, 0.f};

    const int T = Ksub >> 6;   // K-tiles of 64

    // prologue: issue tile 0 into buf 0
#pragma unroll
    for (int i = 0; i < 4; ++i) {
        __builtin_amdgcn_global_load_lds(
            (const __attribute__((address_space(1))) void*)gA[i],
            (__attribute__((address_space(3))) void*)&sh.stage[0][0][ldsOff[i]],
            16, 0, 0);
        __builtin_amdgcn_global_load_lds(
            (const __attribute__((address_space(1))) void*)gB[i],
            (__attribute__((address_space(3))) void*)&sh.stage[0][1][ldsOff[i]],
            16, 0, 0);
        gA[i] += 64;
        gB[i] += 64;
    }

    for (int t = 0; t < T; ++t) {
        // drains vmcnt: tile t ready; also orders all waves past compute t-1
        __syncthreads();
        const int cur = t & 1;
        if (t + 1 < T) {
            const int nxt = cur ^ 1;
#pragma unroll
            for (int i = 0; i < 4; ++i) {
                __builtin_amdgcn_global_load_lds(
                    (const __attribute__((address_space(1))) void*)gA[i],
                    (__attribute__((address_space(3))) void*)&sh.stage[nxt][0][ldsOff[i]],
                    16, 0, 0);
                __builtin_amdgcn_global_load_lds(
                    (const __attribute__((address_space(1))) void*)gB[i],
                    (__attribute__((address_space(3))) void*)&sh.stage[nxt][1][ldsOff[i]],
                    16, 0, 0);
                gA[i] += 64;
                gB[i] += 64;
            }
        }
        const unsigned short* As = sh.stage[cur][0];
        const unsigned short* Bs = sh.stage[cur][1];
#pragma unroll
        for (int kc = 0; kc < 2; ++kc) {       // kk = kc*32
            bf16x8 av[4], bv[4];
#pragma unroll
            for (int r = 0; r < 4; ++r)
                av[r] = *(const bf16x8*)&As[(((kc * 4 + q) * 128) + wm * 64 + r * 16 + col) * 8];
#pragma unroll
            for (int c = 0; c < 4; ++c)
                bv[c] = *(const bf16x8*)&Bs[(((kc * 4 + q) * 128) + wn * 64 + c * 16 + col) * 8];
#pragma unroll
            for (int r = 0; r < 4; ++r)
#pragma unroll
                for (int c = 0; c < 4; ++c)
                    acc[r][c] = __builtin_amdgcn_mfma_f32_16x16x32_bf16(
                        av[r], bv[c], acc[r][c], 0, 0, 0);
        }
    }

    OutT* Cb;
    int ldcl, rowBase, colBase;
    if constexpr (TRI) {
        Cb = C + ((size_t)blockIdx.z * NTRI + tileIdx) * 16384;
        ldcl = 128; rowBase = 0; colBase = 0;
    } else {
        Cb = C + sC * bz + sSplit * sp;
        ldcl = ldc; rowBase = tileM; colBase = tileN;
    }

    // vectorized epilogue: per-wave f32 slice (stride 68), phase-barriered
    float* lws = sh.epi[w];
    const int lr = lane >> 4;      // 0..3
    const int lc = lane & 15;      // 0..15
#pragma unroll
    for (int r = 0; r < 4; ++r) {
        __syncthreads();   // r=0: K-loop LDS reads done; r>0: prev read phase done
#pragma unroll
        for (int c = 0; c < 4; ++c)
#pragma unroll
            for (int v = 0; v < 4; ++v)
                lws[(q * 4 + v) * 68 + c * 16 + col] = acc[r][c][v];
        __syncthreads();   // write phase visible before read phase
#pragma unroll
        for (int p = 0; p < 4; ++p) {
            f32x4 t = *(const f32x4*)&lws[(p * 4 + lr) * 68 + lc * 4];
            int row  = rowBase + wm * 64 + r * 16 + p * 4 + lr;
            int colg = colBase + wn * 64 + lc * 4;
            if constexpr (sizeof(OutT) == 2) {
                u16x4 u;
                u[0] = f2bf(t[0]); u[1] = f2bf(t[1]);
                u[2] = f2bf(t[2]); u[3] = f2bf(t[3]);
                *(u16x4*)&Cb[(size_t)row * ldcl + colg] = u;
            } else {
                *(f32x4*)&Cb[(size_t)row * ldcl + colg] = t;
            }
        }
    }
}

extern "C" void kernel_launch(void* const* d_in, const int* in_sizes, int n_in,
                              void* d_out, int out_size, void* d_ws, size_t ws_size,
                              hipStream_t stream) {
    const float* X = (const float*)d_in[0];   // [4,4096,1024]
    const float* W = (const float*)d_in[1];   // [1024,1024]
    float* out = (float*)d_out;               // [4,4096,1024] fp32

    char* ws = (char*)d_ws;
    unsigned short* Xb = (unsigned short*)(ws);              // 33,554,432  [b][s][h]
    unsigned short* XT = (unsigned short*)(ws + 33554432);   // 33,554,432  [b][h][s]
    unsigned short* WT = (unsigned short*)(ws + 67108864);   //  2,097,152  [h'][o]
    unsigned short* G  = (unsigned short*)(ws + 69206016);   //  8,388,608  [b][o][h]
    unsigned short* MT = (unsigned short*)(ws + 77594624);   //  8,388,608  [b][h''][h]
    // Scratch region (reused serially): G partials then MT partials.
    unsigned short* Gpart  = (unsigned short*)(ws + 85983232); // 16*36*16384*2 = 18,874,368
    unsigned short* MTpart = (unsigned short*)(ws + 85983232); // 2*4*1M*2      = 16,777,216
    // high-water: 104,857,600 bytes < 153,092,096 proven available (R3)

    // 1) casts + transposes
    cast_x_kernel<<<dim3(H_DIM / 32, S_DIM / 32, B_DIM), dim3(32, 8), 0, stream>>>(X, Xb, XT);
    cast_w_kernel<<<dim3(H_DIM / 32, H_DIM / 32, 1), dim3(32, 8), 0, stream>>>(W, WT);

    // 2) G_b = XT_b @ XT_b^T, symmetric: 36 lower-tri tiles, split-K=4 (Ksub=1024,
    //    16 iters), bf16 partials. 576 blocks ~ 2.25/CU (LDS limit is 2).
    gemm_bt_kernel<unsigned short, 4, true, false><<<dim3(NTRI, 1, B_DIM * 4), 256, 0, stream>>>(
        XT, XT, Gpart, S_DIM, S_DIM, S_DIM, 128,
        (size_t)H_DIM * S_DIM, (size_t)H_DIM * S_DIM, 0, 0);
    // 2b) reduce partials + mirror transpose -> bf16 G (full)
    reduce_sym_kernel<4><<<dim3(NTRI, B_DIM), 256, 0, stream>>>(Gpart, G);

    // 3) MT_b = G_b @ WT^T (= G W, G symmetric), split-K=2 (Ksub=512, 8 iters)
    gemm_bt_kernel<unsigned short, 2, false, false><<<dim3(8, 8, B_DIM * 2), 256, 0, stream>>>(
        G, WT, MTpart, H_DIM, H_DIM, H_DIM, H_DIM,
        (size_t)H_DIM * H_DIM, (size_t)0, (size_t)H_DIM * H_DIM,
        (size_t)B_DIM * H_DIM * H_DIM);
    reduce_cast_u16_kernel<2><<<dim3(B_DIM * H_DIM * H_DIM / 4 / 256), 256, 0, stream>>>(
        MTpart, MT, (size_t)B_DIM * H_DIM * H_DIM);

    // 4) att_b = Xb_b @ MT_b^T   [4096 x 1024], K = 1024 (16 iters), fp32 out
    //    SWAPXY: x = M-tile (32), y = N-tile (8) -> A-tile sharers same XCD.
    gemm_bt_kernel<float, 1, false, true><<<dim3(S_DIM / 128, 8, B_DIM), 256, 0, stream>>>(
        Xb, MT, out, H_DIM, H_DIM, H_DIM, H_DIM,
        (size_t)S_DIM * H_DIM, (size_t)H_DIM * H_DIM, (size_t)S_DIM * H_DIM, 0);
}